// Round 6
// baseline (367.967 us; speedup 1.0000x reference)
//
#include <hip/hip_runtime.h>
#include <hip/hip_cooperative_groups.h>

namespace cg = cooperative_groups;

// Shapes (fixed by the reference): B=N=16, C=256, D=512, H=W=16 (HW=256)
#define B_  16
#define N_  16
#define C_  256
#define D_  512
#define HW_ 256

// ws layout (float offsets) — every slot written every call; no memset needed.
#define WS_S      0        // 4096 : s[b,hw]
#define WS_M      4096     // 16   : per-b softmax max (corner max)
#define WS_VFMEAN 4112     // 4096 : mean_hw vf[b,c]
#define WS_ZP     16400    // 512  : Z partials, 32 per b

__device__ __forceinline__ float corner(float tmax, float tmin, float smax, float smin) {
  return fmaxf(fmaxf(tmax * smax, tmax * smin), fmaxf(tmin * smax, tmin * smin));
}

// One cooperative kernel: 512 blocks x 512 threads.
// P1: vfmean (all blocks) ; s[b,:]+m_b (blocks 0..15)
// P2: Z partials (all 512 blocks = 16 b x 32 chunks)
// P3: invZ/m tables (all); vpmean+final (blocks 0..15, LDS-only vpmean);
//     attn streamed by all blocks (32 iters x 8 rows x float4).
__global__ __launch_bounds__(512, 4)
void kFused(const float* __restrict__ vf, const float* __restrict__ vw,
            const float* __restrict__ vb, const float* __restrict__ te,
            const float* __restrict__ mtf, const float* __restrict__ iw,
            const float* __restrict__ ib, float* __restrict__ ws,
            float* __restrict__ out) {
  cg::grid_group grid = cg::this_grid();
  int bid = blockIdx.x, tid = threadIdx.x;
  int w = tid >> 6, lane = tid & 63;

  __shared__ float pcw[8][256];                  // P1 colsum partials (8 KB)
  __shared__ float cw[256];                      // P1 colsum
  __shared__ float sh2[2][256];                  // P1 s halves
  __shared__ float r0[8], r1[8], r2[8], r3[8], r4[8];
  __shared__ __align__(16) float sl[HW_];        // P2 s[b,:]
  __shared__ float zp[512];                      // P3 Z partials
  __shared__ float invZs[16], ms[16];            // P3 tables
  __shared__ __align__(16) float vfm[C_];        // P3 final
  __shared__ __align__(16) float pm[D_];         // P3 vpmean (LDS only)
  __shared__ __align__(16) float aL[D_];         // P3 mtf row

  // ---------------- P1: vfmean (all blocks; 1 row per wave) ----------------
  {
    int row = bid * 8 + w;                       // 0..4095 == b*C_ + c
    float4 v = ((const float4*)vf)[row * 64 + lane];
    float s4 = v.x + v.y + v.z + v.w;
    for (int m = 32; m; m >>= 1) s4 += __shfl_xor(s4, m);
    if (lane == 0) ws[WS_VFMEAN + row] = s4 * (1.0f / HW_);
  }

  // ---------------- P1: s + m_b (blocks 0..15) ----------------
  if (bid < 16) {
    int b = bid;
    // te min/max + sum(vb)
    float mx = -1e30f, mn = 1e30f;
    #pragma unroll
    for (int i = tid; i < N_ * D_; i += 512) {
      float v = te[i];
      mx = fmaxf(mx, v); mn = fminf(mn, v);
    }
    float sb = vb[tid];
    for (int m = 32; m; m >>= 1) {
      mx = fmaxf(mx, __shfl_xor(mx, m));
      mn = fminf(mn, __shfl_xor(mn, m));
      sb += __shfl_xor(sb, m);
    }
    // colsum: cw[c] = sum_d vw[d,c]; depth 64 via 8 d-groups, float4
    {
      const float4* vw4 = (const float4*)vw;     // [512][64]
      int dg = w, c4 = tid & 63;
      float4 p = make_float4(0.f, 0.f, 0.f, 0.f);
      #pragma unroll 8
      for (int d = dg * 64; d < dg * 64 + 64; ++d) {
        float4 v = vw4[d * 64 + c4];
        p.x += v.x; p.y += v.y; p.z += v.z; p.w += v.w;
      }
      pcw[dg][c4 * 4 + 0] = p.x;
      pcw[dg][c4 * 4 + 1] = p.y;
      pcw[dg][c4 * 4 + 2] = p.z;
      pcw[dg][c4 * 4 + 3] = p.w;
    }
    if ((tid & 63) == 0) { r0[w] = mx; r1[w] = mn; r2[w] = sb; }
    __syncthreads();
    float tmax = r0[0], tmin = r1[0]; sb = r2[0];
    #pragma unroll
    for (int k = 1; k < 8; ++k) {
      tmax = fmaxf(tmax, r0[k]); tmin = fminf(tmin, r1[k]); sb += r2[k];
    }
    if (tid < 256) {
      float a = 0.f;
      #pragma unroll
      for (int k = 0; k < 8; ++k) a += pcw[k][tid];
      cw[tid] = a;
    }
    __syncthreads();
    // s-dot: depth-128, 2 c-halves
    {
      int hw = tid & 255, ch = tid >> 8;
      const float* vfb = vf + (size_t)b * C_ * HW_;
      float acc = 0.f;
      #pragma unroll 4
      for (int c = ch * 128; c < ch * 128 + 128; ++c)
        acc += vfb[c * HW_ + hw] * cw[c];
      sh2[ch][hw] = acc;
    }
    __syncthreads();
    float sv = 0.f;
    if (tid < 256) {
      sv = sh2[0][tid] + sh2[1][tid] + sb;
      ws[WS_S + b * HW_ + tid] = sv;
    }
    float smx = (tid < 256) ? sv : -1e30f;
    float smn = (tid < 256) ? sv :  1e30f;
    for (int m = 32; m; m >>= 1) {
      smx = fmaxf(smx, __shfl_xor(smx, m));
      smn = fminf(smn, __shfl_xor(smn, m));
    }
    if ((tid & 63) == 0) { r3[w] = smx; r4[w] = smn; }
    __syncthreads();
    if (tid == 0) {
      smx = fmaxf(fmaxf(r3[0], r3[1]), fmaxf(r3[2], r3[3]));
      smn = fminf(fminf(r4[0], r4[1]), fminf(r4[2], r4[3]));
      ws[WS_M + b] = corner(tmax, tmin, smx, smn);
    }
  }

  __threadfence();
  grid.sync();

  // ---------------- P2: Z partials (all blocks; b=bid>>5, cg=bid&31) -------
  {
    int b = bid >> 5, cg2 = bid & 31;
    if (tid < 256) sl[tid] = ws[WS_S + b * HW_ + tid];
    __syncthreads();
    float m = ws[WS_M + b];
    float t = te[cg2 * 256 + (tid & 255)];
    int hw0 = (tid >> 8) * 128;
    float a0 = 0.f, a1 = 0.f, a2 = 0.f, a3 = 0.f;
    #pragma unroll 4
    for (int h = hw0; h < hw0 + 128; h += 4) {
      a0 += __expf(t * sl[h]     - m);
      a1 += __expf(t * sl[h + 1] - m);
      a2 += __expf(t * sl[h + 2] - m);
      a3 += __expf(t * sl[h + 3] - m);
    }
    float z = (a0 + a1) + (a2 + a3);
    for (int m2 = 32; m2; m2 >>= 1) z += __shfl_xor(z, m2);
    if (lane == 0) r0[w] = z;
    __syncthreads();
    if (tid == 0) {
      float zt = 0.f;
      #pragma unroll
      for (int k = 0; k < 8; ++k) zt += r0[k];
      ws[WS_ZP + bid] = zt;
    }
  }

  __threadfence();
  grid.sync();

  // ---------------- P3 prologue: invZ + m tables (every block) -------------
  zp[tid] = ws[WS_ZP + tid];
  __syncthreads();
  if (tid < 16) {
    float s = 0.f;
    #pragma unroll
    for (int k = 0; k < 32; ++k) s += zp[tid * 32 + k];
    invZs[tid] = 1.0f / s;
    ms[tid] = ws[WS_M + tid];
  }
  __syncthreads();

  // ---------------- P3: vpmean + final (blocks 0..15; LDS-only vpmean) -----
  if (bid < 16) {
    int b = bid;
    if (tid < 256) vfm[tid] = ws[WS_VFMEAN + b * C_ + tid];
    aL[tid] = mtf[b * D_ + tid];
    __syncthreads();
    {
      int dd = tid;
      float acc = vb[dd];
      const float4* row4 = (const float4*)(vw + (size_t)dd * C_);
      const float4* v4   = (const float4*)vfm;
      #pragma unroll 4
      for (int c4 = 0; c4 < C_ / 4; ++c4) {
        float4 wv = row4[c4], av = v4[c4];
        acc += av.x * wv.x + av.y * wv.y + av.z * wv.z + av.w * wv.w;
      }
      pm[dd] = acc;
    }
    __syncthreads();
    {
      int d = tid;
      float acc = ib[d];
      const float4* row4 = (const float4*)(iw + (size_t)d * (2 * D_));
      const float4* a4 = (const float4*)aL;
      const float4* p4 = (const float4*)pm;
      #pragma unroll 4
      for (int c4 = 0; c4 < D_ / 4; ++c4) {
        float4 w1 = row4[c4],          av = a4[c4];
        float4 w2 = row4[D_ / 4 + c4], pv = p4[c4];
        acc += av.x * w1.x + av.y * w1.y + av.z * w1.z + av.w * w1.w;
        acc += pv.x * w2.x + pv.y * w2.y + pv.z * w2.z + pv.w * w2.w;
      }
      out[b * D_ + d] = acc;
    }
  }

  // ---------------- P3: attn (all blocks; 32 iters x 8 rows x float4) ------
  {
    float* attn = out + N_ * D_;
    #pragma unroll 2
    for (int k = 0; k < 32; ++k) {
      int row = bid * 8 + w + k * 4096;          // 0..131071 = b*8192 + nd
      int b2 = row >> 13;
      float t = te[row & (N_ * D_ - 1)];
      float4 sv = ((const float4*)(ws + WS_S + b2 * HW_))[lane];
      float m2 = ms[b2], iz = invZs[b2];
      float4 o;
      o.x = __expf(t * sv.x - m2) * iz;
      o.y = __expf(t * sv.y - m2) * iz;
      o.z = __expf(t * sv.z - m2) * iz;
      o.w = __expf(t * sv.w - m2) * iz;
      ((float4*)(attn + (size_t)row * HW_))[lane] = o;
    }
  }
}

extern "C" void kernel_launch(void* const* d_in, const int* in_sizes, int n_in,
                              void* d_out, int out_size, void* d_ws, size_t ws_size,
                              hipStream_t stream) {
  const float* mtf = (const float*)d_in[0];  // masked_text_features [16,512]
  const float* vf  = (const float*)d_in[1];  // visual_features [16,256,16,16]
  const float* te  = (const float*)d_in[2];  // text_embeddings [16,512]
  const float* vw  = (const float*)d_in[3];  // visual_proj_w [512,256]
  const float* vb  = (const float*)d_in[4];  // visual_proj_b [512]
  const float* iw  = (const float*)d_in[5];  // interaction_w [512,1024]
  const float* ib  = (const float*)d_in[6];  // interaction_b [512]
  float* out = (float*)d_out;
  float* ws  = (float*)d_ws;

  void* args[] = {(void*)&vf, (void*)&vw, (void*)&vb, (void*)&te,
                  (void*)&mtf, (void*)&iw, (void*)&ib, (void*)&ws, (void*)&out};
  hipLaunchCooperativeKernel((const void*)kFused, dim3(512), dim3(512),
                             args, 0, stream);
}

// Round 8
// 74.356 us; speedup vs baseline: 4.9487x; 4.9487x over previous
//
#include <hip/hip_runtime.h>

// Shapes (fixed by the reference): B=N=16, C=256, D=512, H=W=16 (HW=256)
#define B_  16
#define N_  16
#define C_  256
#define D_  512
#define HW_ 256

typedef float f32x4 __attribute__((ext_vector_type(4)));

// ws layout (float offsets) — every slot written every call; no memset needed.
#define WS_S      0        // 4096 : s[b,hw]
#define WS_M      4096     // 16   : per-b softmax max (corner max)
#define WS_VFMEAN 4112     // 4096 : mean_hw vf[b,c]
#define WS_VPMEAN 8208     // 8192 : vpmean[b,d]
#define WS_ZP     16400    // 512  : Z partials, 32 per b

__device__ __forceinline__ float corner(float tmax, float tmin, float smax, float smin) {
  return fmaxf(fmaxf(tmax * smax, tmax * smin), fmaxf(tmin * smax, tmin * smin));
}

// ---------------- kA: 512-thread blocks (byte-identical to R5) -------------
// blocks 0..15   : s[b,:] + m_b  (own colsum, shallow-depth)
// blocks 16..527 : vfmean, 8 rows per block (coalesced float4 wave-reduce)
__global__ void kA(const float* __restrict__ vf, const float* __restrict__ vw,
                   const float* __restrict__ vb, const float* __restrict__ te,
                   float* __restrict__ ws) {
  int bid = blockIdx.x, tid = threadIdx.x;

  if (bid < 16) {
    int b = bid;
    int w = tid >> 6;                 // wave id 0..7
    __shared__ float pcw[8][256];     // colsum partials
    __shared__ float cw[256];
    __shared__ float sh2[2][256];
    __shared__ float r0[8], r1[8], r2[8], r3[8], r4[8];

    // --- te min/max + sum(vb), block-wide (cheap: depth 16 / 1) ---
    float mx = -1e30f, mn = 1e30f;
    #pragma unroll
    for (int i = tid; i < N_ * D_; i += 512) {
      float v = te[i];
      mx = fmaxf(mx, v); mn = fminf(mn, v);
    }
    float sb = vb[tid];
    for (int m = 32; m; m >>= 1) {
      mx = fmaxf(mx, __shfl_xor(mx, m));
      mn = fminf(mn, __shfl_xor(mn, m));
      sb += __shfl_xor(sb, m);
    }

    // --- colsum: cw[c] = sum_d vw[d,c]; depth 64 via 8 d-groups, float4 ---
    {
      const float4* vw4 = (const float4*)vw;     // [512][64]
      int dg = w, c4 = tid & 63;
      float4 p = make_float4(0.f, 0.f, 0.f, 0.f);
      #pragma unroll 8
      for (int d = dg * 64; d < dg * 64 + 64; ++d) {
        float4 v = vw4[d * 64 + c4];
        p.x += v.x; p.y += v.y; p.z += v.z; p.w += v.w;
      }
      pcw[dg][c4 * 4 + 0] = p.x;
      pcw[dg][c4 * 4 + 1] = p.y;
      pcw[dg][c4 * 4 + 2] = p.z;
      pcw[dg][c4 * 4 + 3] = p.w;
    }
    if ((tid & 63) == 0) { r0[w] = mx; r1[w] = mn; r2[w] = sb; }
    __syncthreads();
    float tmax = r0[0], tmin = r1[0]; sb = r2[0];
    #pragma unroll
    for (int k = 1; k < 8; ++k) {
      tmax = fmaxf(tmax, r0[k]); tmin = fminf(tmin, r1[k]); sb += r2[k];
    }
    if (tid < 256) {
      float a = 0.f;
      #pragma unroll
      for (int k = 0; k < 8; ++k) a += pcw[k][tid];
      cw[tid] = a;
    }
    __syncthreads();

    // --- s[b,hw]: depth-128 dot, 2 c-halves per hw ---
    {
      int hw = tid & 255, ch = tid >> 8;   // ch in {0,1}
      const float* vfb = vf + (size_t)b * C_ * HW_;
      float acc = 0.f;
      #pragma unroll 4
      for (int c = ch * 128; c < ch * 128 + 128; ++c)
        acc += vfb[c * HW_ + hw] * cw[c];
      sh2[ch][hw] = acc;
    }
    __syncthreads();

    float sv = 0.f;
    if (tid < 256) {
      sv = sh2[0][tid] + sh2[1][tid] + sb;
      ws[WS_S + b * HW_ + tid] = sv;
    }
    // per-b s min/max over threads 0..255 (waves 0..3)
    float smx = (tid < 256) ? sv : -1e30f;
    float smn = (tid < 256) ? sv :  1e30f;
    for (int m = 32; m; m >>= 1) {
      smx = fmaxf(smx, __shfl_xor(smx, m));
      smn = fminf(smn, __shfl_xor(smn, m));
    }
    if ((tid & 63) == 0) { r3[w] = smx; r4[w] = smn; }
    __syncthreads();
    if (tid == 0) {
      smx = fmaxf(fmaxf(r3[0], r3[1]), fmaxf(r3[2], r3[3]));
      smn = fminf(fminf(r4[0], r4[1]), fminf(r4[2], r4[3]));
      ws[WS_M + b] = corner(tmax, tmin, smx, smn);
    }
    return;
  }

  // vfmean: one wave per (b,c) row, 8 rows per block
  {
    int row  = (bid - 16) * 8 + (tid >> 6);   // b*C_ + c, 4096 rows
    int lane = tid & 63;
    float4 v = ((const float4*)(vf + (size_t)row * HW_))[lane];
    float s = v.x + v.y + v.z + v.w;
    for (int m = 32; m; m >>= 1) s += __shfl_xor(s, m);
    if (lane == 0) ws[WS_VFMEAN + row] = s * (1.0f / HW_);
  }
}

// ---------------- kB: 256-thread blocks (byte-identical to R5) -------------
// blocks 0..511  : Z partials (pure exp; s,m read from ws)
// blocks 512..543: vpmean
__global__ void kB(const float* __restrict__ vw, const float* __restrict__ vb,
                   const float* __restrict__ te, float* __restrict__ ws) {
  int bid = blockIdx.x, tid = threadIdx.x;
  if (bid < 512) {
    int b = bid >> 5, chunk = bid & 31;
    __shared__ float sl[HW_];
    __shared__ float part[4];
    sl[tid] = ws[WS_S + b * HW_ + tid];
    __syncthreads();
    float m = ws[WS_M + b];
    float t = te[chunk * 256 + tid];
    float zacc = 0.f;
    #pragma unroll 4
    for (int hw = 0; hw < HW_; ++hw) zacc += __expf(t * sl[hw] - m);
    for (int mm = 32; mm; mm >>= 1) zacc += __shfl_xor(zacc, mm);
    if ((tid & 63) == 0) part[tid >> 6] = zacc;
    __syncthreads();
    if (tid == 0) ws[WS_ZP + bid] = part[0] + part[1] + part[2] + part[3];
    return;
  }
  // vpmean[b,dd] = dot(vfmean[b,:], vw[dd,:]) + vb[dd]
  {
    int id = (bid - 512) * 256 + tid;
    int b = id >> 9, dd = id & (D_ - 1);
    __shared__ __align__(16) float vfm[C_];
    vfm[tid] = ws[WS_VFMEAN + b * C_ + tid];
    __syncthreads();
    float acc = vb[dd];
    const float4* row4 = (const float4*)(vw + (size_t)dd * C_);
    const float4* v4   = (const float4*)vfm;
    #pragma unroll 4
    for (int c4 = 0; c4 < C_ / 4; ++c4) {
      float4 wv = row4[c4], av = v4[c4];
      acc += av.x * wv.x + av.y * wv.y + av.z * wv.z + av.w * wv.w;
    }
    ws[WS_VPMEAN + id] = acc;
  }
}

// ---------------- kD: final (blocks 0..31), attn (blocks 32..2079, 64 rows
// each, nontemporal f32x4 stores) -------------------------------------------
__global__ __launch_bounds__(256)
void kD(const float* __restrict__ te, const float* __restrict__ mtf,
        const float* __restrict__ iw, const float* __restrict__ ib,
        const float* __restrict__ ws, float* __restrict__ out) {
  int bid = blockIdx.x, tid = threadIdx.x;
  if (bid < 32) {
    // final[b,d] = mtf[b,:].iw[d,0:512] + vpmean[b,:].iw[d,512:1024] + ib[d]
    int id = bid * 256 + tid;
    int b = id >> 9, d = id & (D_ - 1);
    __shared__ __align__(16) float a[D_], p[D_];
    a[tid]       = mtf[b * D_ + tid];
    a[tid + 256] = mtf[b * D_ + tid + 256];
    p[tid]       = ws[WS_VPMEAN + b * D_ + tid];
    p[tid + 256] = ws[WS_VPMEAN + b * D_ + tid + 256];
    __syncthreads();
    float acc = ib[d];
    const float4* row4 = (const float4*)(iw + (size_t)d * (2 * D_));
    const float4* a4 = (const float4*)a;
    const float4* p4 = (const float4*)p;
    #pragma unroll 4
    for (int c4 = 0; c4 < D_ / 4; ++c4) {
      float4 w1 = row4[c4],            av = a4[c4];
      float4 w2 = row4[D_ / 4 + c4],   pv = p4[c4];
      acc += av.x * w1.x + av.y * w1.y + av.z * w1.z + av.w * w1.w;
      acc += pv.x * w2.x + pv.y * w2.y + pv.z * w2.z + pv.w * w2.w;
    }
    out[id] = acc;
    return;
  }
  // attn: 2048 blocks x 64 rows each
  int r0 = (bid - 32) * 64;           // global row = b*8192 + nd
  int b = r0 >> 13;                   // 64-row blocks never straddle a b
  __shared__ __align__(16) float sl[HW_];
  __shared__ float sinvZ;
  sl[tid] = ws[WS_S + b * HW_ + tid];
  if (tid < 32) {
    float pz = ws[WS_ZP + b * 32 + tid];
    #pragma unroll
    for (int m = 16; m; m >>= 1) pz += __shfl_xor(pz, m);
    if (tid == 0) sinvZ = 1.0f / pz;
  }
  __syncthreads();
  float m = ws[WS_M + b];
  float invZ = sinvZ;
  int lane = tid & 63;
  int w = tid >> 6;
  float4 sv = ((const float4*)sl)[lane];
  float* attn = out + N_ * D_;        // skip final (8192 floats)
  #pragma unroll 4
  for (int k = 0; k < 16; ++k) {
    int row = r0 + w + k * 4;
    float t = te[row & (N_ * D_ - 1)];
    f32x4 o;
    o.x = __expf(t * sv.x - m) * invZ;
    o.y = __expf(t * sv.y - m) * invZ;
    o.z = __expf(t * sv.z - m) * invZ;
    o.w = __expf(t * sv.w - m) * invZ;
    __builtin_nontemporal_store(o, (f32x4*)(attn + (size_t)row * HW_) + lane);
  }
}

extern "C" void kernel_launch(void* const* d_in, const int* in_sizes, int n_in,
                              void* d_out, int out_size, void* d_ws, size_t ws_size,
                              hipStream_t stream) {
  const float* mtf = (const float*)d_in[0];  // masked_text_features [16,512]
  const float* vf  = (const float*)d_in[1];  // visual_features [16,256,16,16]
  const float* te  = (const float*)d_in[2];  // text_embeddings [16,512]
  const float* vw  = (const float*)d_in[3];  // visual_proj_w [512,256]
  const float* vb  = (const float*)d_in[4];  // visual_proj_b [512]
  const float* iw  = (const float*)d_in[5];  // interaction_w [512,1024]
  const float* ib  = (const float*)d_in[6];  // interaction_b [512]
  float* out = (float*)d_out;
  float* ws  = (float*)d_ws;

  kA<<<528, 512, 0, stream>>>(vf, vw, vb, te, ws);
  kB<<<544, 256, 0, stream>>>(vw, vb, te, ws);
  kD<<<2080, 256, 0, stream>>>(te, mtf, iw, ib, ws, out);
}